// Round 11
// baseline (123.026 us; speedup 1.0000x reference)
//
#include <hip/hip_runtime.h>
#include <stdint.h>

// Problem constants
#define B_  32
#define S_  512
#define C_  320
#define H_  512

typedef __attribute__((ext_vector_type(8))) short short8;
typedef __attribute__((ext_vector_type(4))) float f32x4;

__device__ __forceinline__ unsigned f2bf(float x){
  unsigned u = __builtin_bit_cast(unsigned, x);
  u = u + 0x7FFFu + ((u >> 16) & 1u);          // round-to-nearest-even
  return u >> 16;
}
__device__ __forceinline__ float sigf(float x){ return 1.0f/(1.0f + __expf(-x)); }
__device__ __forceinline__ float tanh_fast(float x){ return 2.0f/(1.0f + __expf(-2.0f*x)) - 1.0f; }

__device__ __forceinline__ void gload16(const void* g, void* l){
  __builtin_amdgcn_global_load_lds((const __attribute__((address_space(1))) void*)g,
                                   (__attribute__((address_space(3))) void*)l, 16, 0, 0);
}

// ============================================================================
// SINGLE-DISPATCH fused kernel. Grid 256 x 256thr, 160KB LDS -> exactly
// 1 block/CU, all blocks co-resident -> manual device-scope grid barrier is
// deadlock-free. Phase 1: w-cast (3 jobs/block) + x transpose-cast into
// xws2[n'=c*32+b][s] (5 jobs/block). Grid barrier (threadfence release ->
// agent-scope atomic arrive -> acquire spin). Phase 2: block (mt,ng) stages
// its 96KB A-slab ONCE, loops 10 N-tiles: stage 64KB B, 16-ks MFMA sweep,
// LSTM epilogue -> LDS f32 transpose -> coalesced f32 out.
// ============================================================================
__global__ __launch_bounds__(256, 1) void k_fused(const float* __restrict__ w,
                                                  const float* __restrict__ x,
                                                  const float* __restrict__ b_ih,
                                                  const float* __restrict__ b_hh,
                                                  unsigned short* __restrict__ aws,
                                                  unsigned short* __restrict__ xws,
                                                  unsigned* __restrict__ bar,
                                                  float* __restrict__ out){
  __shared__ union {
    float t[64][65];          // phase-1 transpose tile (16.6 KB)
    char  raw[163840];        // phase-2: A [3][32][1024B] at 0, B [64][1024B] at 98304
  } sm;

  const int bid = blockIdx.x;                  // 0..255
  const int tid = threadIdx.x;

  // ---------------- phase 1a: compact+cast w_ih -> aws[3][512][512] --------
  #pragma unroll
  for (int i = 0; i < 3; i++){
    int flat  = (bid*3 + i)*256 + tid;         // 0..196607 float4 units
    int plane = flat >> 16;
    int rem   = flat & 65535;
    int srow  = (plane == 0 ? 0 : (plane == 1 ? 1024 : 1536));
    float4 v = ((const float4*)w)[srow*128 + rem];
    uint2 p;
    p.x = f2bf(v.x) | (f2bf(v.y) << 16);
    p.y = f2bf(v.z) | (f2bf(v.w) << 16);
    ((uint2*)aws)[flat] = p;
  }

  // ---------------- phase 1b: x (b,s,c) f32 -> xws2[c*32+b][s] bf16 --------
  for (int jj = 0; jj < 5; jj++){
    const int idx = bid*5 + jj;                // 0..1279 = st + 8*(ctt + 5*b)
    const int st = idx & 7;
    const int r5 = idx >> 3;
    const int ctt = r5 % 5, b = r5 / 5;
    const int s0 = st*64, c0 = ctt*64;
    const int row = tid >> 2, q = tid & 3;

    const float* src = x + ((size_t)(b*S_ + s0 + row))*C_ + c0 + q*16;
    #pragma unroll
    for (int j = 0; j < 4; j++){
      float4 v = ((const float4*)src)[j];
      sm.t[row][q*16 + j*4 + 0] = v.x;
      sm.t[row][q*16 + j*4 + 1] = v.y;
      sm.t[row][q*16 + j*4 + 2] = v.z;
      sm.t[row][q*16 + j*4 + 3] = v.w;
    }
    __syncthreads();
    // coalesced write: 8 lanes cover one n'-row's 64 s-elems (128B run)
    const int wr2 = tid >> 3;                  // 0..31
    const int l8  = tid & 7;
    #pragma unroll
    for (int half = 0; half < 2; half++){
      const int crow = half*32 + wr2;          // 0..63
      const size_t nprime = (size_t)(c0 + crow)*32 + (size_t)b;
      short8 o;
      #pragma unroll
      for (int e = 0; e < 8; e++)
        o[e] = (short)f2bf(sm.t[l8*8 + e][crow]);
      *(short8*)(xws + nprime*S_ + s0 + l8*8) = o;
    }
    __syncthreads();                           // LDS reused next job
  }

  // ---------------- grid barrier (all 256 blocks co-resident) --------------
  __threadfence();                             // release: publish aws/xws device-wide
  __syncthreads();                             // all threads' fences done
  if (tid == 0){
    __hip_atomic_fetch_add(bar, 1u, __ATOMIC_ACQ_REL, __HIP_MEMORY_SCOPE_AGENT);
    while (__hip_atomic_load(bar, __ATOMIC_ACQUIRE, __HIP_MEMORY_SCOPE_AGENT) < 256u)
      __builtin_amdgcn_s_sleep(32);
  }
  __syncthreads();

  // ---------------- phase 2: GEMM, block = (mt, ng), 10 N-tiles ------------
  // bid = mt*16 + ng  ->  bid&7 = ng&7: all 16 mt-blocks of one ng share an
  // XCD (B-slice L2 reuse, ~1.25MB/XCD).
  const int w_   = tid >> 6;
  const int lane = tid & 63;
  const int wm = w_ >> 1, wn = w_ & 1;
  const int mt = bid >> 4;                     // 0..15
  const int ng = bid & 15;                     // 0..15
  const int k0 = mt*32;

  const char* wsb = (const char*)aws;

  // stage A-slab once: 96 row-chunks (3 gates x 32 rows x 1024B), 24/wave.
  // source pre-swizzled (lane*16)^((row&7)<<4); LDS dest linear.
  #pragma unroll
  for (int i = 0; i < 24; i++){
    const int q  = i*4 + w_;
    const int gi = q >> 5, row = q & 31;
    const int slot = (lane << 4) ^ ((row & 7) << 4);
    const unsigned src = (unsigned)((gi*512 + k0 + row)*1024 + slot);
    gload16(wsb + (size_t)src, sm.raw + gi*32768 + row*1024);
  }

  // hoisted biases (mt fixed for the whole block)
  const int kbl = wm*16 + ((lane >> 4) << 2);  // local k, + r
  const int kg  = k0 + kbl;
  float bi[4], bg[4], bo[4];
  #pragma unroll
  for (int r = 0; r < 4; r++){
    bi[r] = b_ih[kg + r]        + b_hh[kg + r];
    bg[r] = b_ih[1024 + kg + r] + b_hh[1024 + kg + r];
    bo[r] = b_ih[1536 + kg + r] + b_hh[1536 + kg + r];
  }

  const int l15   = lane & 15;
  const int hi16  = (lane >> 4) << 4;
  const int xkey  = (l15 & 7) << 4;
  const int arow  = wm*16 + l15;
  const int brow0 = wn*32 + l15;
  const int klo   = tid >> 3;                  // store phase: k-row 0..31
  const int lane8 = tid & 7;
  const size_t rowoff = (size_t)(k0 + klo)*C_;

  for (int it = 0; it < 10; it++){
    const int nt = ng*10 + it;                 // 0..159
    const int nbase = nt*64;

    // stage B-slice: 64 row-chunks, 16/wave
    #pragma unroll
    for (int i = 0; i < 16; i++){
      const int row = i*4 + w_;
      const int slot = (lane << 4) ^ ((row & 7) << 4);
      const unsigned src = 2097152u + (unsigned)((nbase + row)*1024 + slot);
      gload16(wsb + (size_t)src, sm.raw + 98304 + row*1024);
    }
    __syncthreads();                           // stage drained (A too on it=0)

    f32x4 acc[3][2];
    #pragma unroll
    for (int gi = 0; gi < 3; gi++)
      #pragma unroll
      for (int nf = 0; nf < 2; nf++)
        acc[gi][nf] = (f32x4){0.f, 0.f, 0.f, 0.f};

    #pragma unroll
    for (int ks = 0; ks < 16; ks++){
      const int colb = (ks*64 + hi16) ^ xkey;
      short8 aF[3], bF[2];
      #pragma unroll
      for (int gi = 0; gi < 3; gi++)
        aF[gi] = *(const short8*)(sm.raw + gi*32768 + arow*1024 + colb);
      #pragma unroll
      for (int nf = 0; nf < 2; nf++)
        bF[nf] = *(const short8*)(sm.raw + 98304 + (brow0 + nf*16)*1024 + colb);
      #pragma unroll
      for (int gi = 0; gi < 3; gi++)
        #pragma unroll
        for (int nf = 0; nf < 2; nf++)
          acc[gi][nf] = __builtin_amdgcn_mfma_f32_16x16x32_bf16(aF[gi], bF[nf], acc[gi][nf], 0, 0, 0);
    }
    __syncthreads();                           // B reads done (region reusable)

    // epilogue: gates -> h -> tr[32 k][68] f32 in the B region
    float* tr = (float*)(sm.raw + 98304);
    #pragma unroll
    for (int nf = 0; nf < 2; nf++){
      const int nl = wn*32 + nf*16 + l15;      // local n' 0..63
      #pragma unroll
      for (int r = 0; r < 4; r++){
        float iv = acc[0][nf][r] + bi[r];
        float gv = acc[1][nf][r] + bg[r];
        float ov = acc[2][nf][r] + bo[r];
        float ce = sigf(iv) * tanh_fast(gv);
        tr[(kbl + r)*68 + nl] = sigf(ov) * tanh_fast(ce);
      }
    }
    __syncthreads();

    // coalesced store: thread t -> k-row t>>3; 8 lanes cover 32 consecutive
    // n' (128B) per j; a 64-run never crosses a b2 boundary.
    #pragma unroll
    for (int j = 0; j < 2; j++){
      const int nl0 = j*32 + lane8*4;
      const int ngl = nbase + nl0;             // global n' = b2*320 + c2
      const int b2  = ngl / 320;
      const int c2  = ngl - b2*320;
      float4 v;
      v.x = tr[klo*68 + nl0 + 0];
      v.y = tr[klo*68 + nl0 + 1];
      v.z = tr[klo*68 + nl0 + 2];
      v.w = tr[klo*68 + nl0 + 3];
      *(float4*)(out + (size_t)b2*(H_*C_) + rowoff + c2) = v;
    }
    __syncthreads();                           // tr reads done before next B
  }
}

extern "C" void kernel_launch(void* const* d_in, const int* in_sizes, int n_in,
                              void* d_out, int out_size, void* d_ws, size_t ws_size,
                              hipStream_t stream){
  const float* x    = (const float*)d_in[0];
  const float* w_ih = (const float*)d_in[1];
  // d_in[2] = w_hh is mathematically dead (h0 = 0)
  const float* b_ih = (const float*)d_in[3];
  const float* b_hh = (const float*)d_in[4];
  float* out = (float*)d_out;

  char* ws = (char*)d_ws;
  unsigned short* aws = (unsigned short*)(ws);                 // 1.5 MiB
  unsigned short* xws = (unsigned short*)(ws + 2097152);       // 10 MiB, n'-layout
  unsigned* bar = (unsigned*)(ws + 12582912);                  // 4B barrier counter

  hipMemsetAsync(bar, 0, 4, stream);                           // graph-capturable
  k_fused<<<256, 256, 0, stream>>>(w_ih, x, b_ih, b_hh, aws, xws, bar, out);
}

// Round 12
// 56.686 us; speedup vs baseline: 2.1703x; 2.1703x over previous
//
#include <hip/hip_runtime.h>
#include <stdint.h>

// Problem constants
#define B_  32
#define S_  512
#define C_  320
#define H_  512

typedef __attribute__((ext_vector_type(8))) short short8;
typedef __attribute__((ext_vector_type(4))) float f32x4;

__device__ __forceinline__ unsigned f2bf(float x){
  unsigned u = __builtin_bit_cast(unsigned, x);
  u = u + 0x7FFFu + ((u >> 16) & 1u);          // round-to-nearest-even
  return u >> 16;
}
__device__ __forceinline__ float bf2f(unsigned short h){
  unsigned u = ((unsigned)h) << 16;
  return __builtin_bit_cast(float, u);
}
__device__ __forceinline__ float sigf(float x){ return 1.0f/(1.0f + __expf(-x)); }
__device__ __forceinline__ float tanh_fast(float x){ return 2.0f/(1.0f + __expf(-2.0f*x)) - 1.0f; }

__device__ __forceinline__ void gload16(const void* g, void* l){
  __builtin_amdgcn_global_load_lds((const __attribute__((address_space(1))) void*)g,
                                   (__attribute__((address_space(3))) void*)l, 16, 0, 0);
}

// ---- Pass 0 (fused): blocks 0..767 cast w_ih; blocks 768..2047 cast+T x ----
// x part writes xws2[n'][s], n' = c*32 + b (scramble folded into the layout).
__global__ __launch_bounds__(256) void k_prep(const float* __restrict__ w,
                                              const float* __restrict__ x,
                                              unsigned short* __restrict__ aws,
                                              unsigned short* __restrict__ xws){
  const int bidg = blockIdx.x;
  const int tid = threadIdx.x;
  if (bidg < 768){
    int flat = bidg*256 + tid;                 // float4 units; 3*512*512/4 = 196608
    int plane = flat >> 16;
    int rem   = flat & 65535;
    int srow  = (plane == 0 ? 0 : (plane == 1 ? 1024 : 1536));
    float4 v = ((const float4*)w)[srow*128 + rem];
    uint2 p;
    p.x = f2bf(v.x) | (f2bf(v.y) << 16);
    p.y = f2bf(v.z) | (f2bf(v.w) << 16);
    ((uint2*)aws)[flat] = p;
    return;
  }
  __shared__ float lds[64][65];
  const int idx = bidg - 768;                  // 0..1279 = st + 8*(ctt + 5*b)
  const int st = idx & 7;
  const int r5 = idx >> 3;
  const int ctt = r5 % 5, b = r5 / 5;
  const int s0 = st*64, c0 = ctt*64;
  const int row = tid >> 2, q = tid & 3;

  const float* src = x + ((size_t)(b*S_ + s0 + row))*C_ + c0 + q*16;
  #pragma unroll
  for (int j = 0; j < 4; j++){
    float4 v = ((const float4*)src)[j];
    lds[row][q*16 + j*4 + 0] = v.x;
    lds[row][q*16 + j*4 + 1] = v.y;
    lds[row][q*16 + j*4 + 2] = v.z;
    lds[row][q*16 + j*4 + 3] = v.w;
  }
  __syncthreads();
  // coalesced write: 8 lanes cover one n'-row's 64 s-elems (128B run)
  const int wr2 = tid >> 3;                    // 0..31
  const int l8  = tid & 7;
  #pragma unroll
  for (int half = 0; half < 2; half++){
    const int crow = half*32 + wr2;            // 0..63
    const size_t nprime = (size_t)(c0 + crow)*32 + (size_t)b;
    short8 o;
    #pragma unroll
    for (int e = 0; e < 8; e++)
      o[e] = (short)f2bf(lds[l8*8 + e][crow]);
    *(short8*)(xws + nprime*S_ + s0 + l8*8) = o;
  }
}

// ---- Pass 1: barrier-free wave-independent MFMA GEMM + LSTM epilogue -------
// GEMM: M=1536 (3g x 512k), N=10240 (n' order), K=512. Each WAVE owns one
// 96M (3g x 32k) x 64N tile with PRIVATE 20KB LDS -> NO __syncthreads
// anywhere. Per K-step (BK=64): vmcnt(0) [own stage landed] -> read all 20
// frags to regs -> lgkmcnt(0) -> issue next step's 20 global_load_lds into
// the SAME region (single-buffered but overlapped: frags already in regs)
// -> 48 MFMA while loads fly. Waves drift out of phase -> 8 independent
// waves/CU give the scheduler cover for every stage latency (m114 mechanism;
// the barrier-locked variants R1-R10 could never use it).
// 640 blocks x 256 thr (4 waves), LDS 80KB -> 2 blocks/CU.
__global__ __launch_bounds__(256, 2) void k_gemm(const unsigned short* __restrict__ aws,
                                                 const unsigned short* __restrict__ xws,
                                                 const float* __restrict__ b_ih,
                                                 const float* __restrict__ b_hh,
                                                 unsigned short* __restrict__ hws){
  // per-wave region (20480B): A [3 gate][4 chunk][1024B] at 0..12288 (row pitch
  // 128B), B [8 chunk][1024B] at 12288..20480
  __shared__ alignas(16) char lds[4][20480];

  const int tid  = threadIdx.x;
  const int w    = tid >> 6;
  const int lane = tid & 63;
  char* wb = &lds[w][0];

  const int wt = blockIdx.x*4 + w;             // 0..2559 wave-tiles
  const int mt = wt & 15;                      // 16 M-tiles (32 k-rows x 3 gates)
  const int nt = wt >> 4;                      // 160 N-tiles (64 n')
  const int k0 = mt*32;                        // gate-local k base
  const int nbase = nt*64;

  f32x4 acc[3][2][4];
  #pragma unroll
  for (int gi = 0; gi < 3; gi++)
    #pragma unroll
    for (int mf = 0; mf < 2; mf++)
      #pragma unroll
      for (int nf = 0; nf < 4; nf++)
        acc[gi][mf][nf] = (f32x4){0.f, 0.f, 0.f, 0.f};

  // staging: chunk = 8 rows x 128B = 1KB per gload16.
  // LDS slot (row, colb) holds global element (row, colb ^ ((row&7)<<4))
  // (verified R6 algebra; 128B row pitch -> quarter-wave 2-way = conflict-free)
  const int cr   = lane >> 3;
  const int slot = ((lane & 7) ^ cr) << 4;

  const char* wsb = (const char*)aws;
  unsigned srcoff[20];
  #pragma unroll
  for (int i = 0; i < 20; i++){
    if (i < 12){
      int gi = i >> 2, q8 = i & 3;             // 4 chunks x 8 rows = 32 k-rows
      int grow = gi*512 + k0 + q8*8 + cr;
      srcoff[i] = (unsigned)(grow*1024 + slot);              // aws at ws+0
    } else {
      int q8 = i - 12;                         // 8 chunks x 8 rows = 64 n'-rows
      int xrow = nbase + q8*8 + cr;
      srcoff[i] = (unsigned)(2097152 + xrow*1024 + slot);    // xws2 at ws+2MiB
    }
  }
  // LDS dest byte offsets (compile-time per i): A gi*4096+q8*1024; B 12288+q8*1024

  // prologue: stage step 0
  #pragma unroll
  for (int i = 0; i < 20; i++){
    const int d = (i < 12) ? ((i >> 2)*4096 + (i & 3)*1024) : (12288 + (i - 12)*1024);
    gload16(wsb + (size_t)srcoff[i], wb + d);
    srcoff[i] += 128;
  }

  const int lo16 = (lane >> 4) << 4;
  const int swz  = (lane & 7) << 4;
  const int l15  = lane & 15;

  #pragma unroll
  for (int t = 0; t < 8; t++){
    // own stage landed (wave-private wait, no barrier)
    asm volatile("s_waitcnt vmcnt(0)" ::: "memory");
    __builtin_amdgcn_sched_barrier(0);

    // read ALL fragments for this step (both K-halves) into registers
    short8 aF[2][3][2], bF[2][4];
    #pragma unroll
    for (int ks = 0; ks < 2; ks++){
      const int colb = (ks*64 + lo16) ^ swz;
      #pragma unroll
      for (int gi = 0; gi < 3; gi++)
        #pragma unroll
        for (int mf = 0; mf < 2; mf++)
          aF[ks][gi][mf] = *(const short8*)(wb + gi*4096 + (mf*16 + l15)*128 + colb);
      #pragma unroll
      for (int nf = 0; nf < 4; nf++)
        bF[ks][nf] = *(const short8*)(wb + 12288 + (nf*16 + l15)*128 + colb);
    }
    asm volatile("s_waitcnt lgkmcnt(0)" ::: "memory");
    __builtin_amdgcn_sched_barrier(0);

    // issue next step's stage into the just-consumed region; overlaps MFMAs
    if (t < 7){
      #pragma unroll
      for (int i = 0; i < 20; i++){
        const int d = (i < 12) ? ((i >> 2)*4096 + (i & 3)*1024) : (12288 + (i - 12)*1024);
        gload16(wsb + (size_t)srcoff[i], wb + d);
        srcoff[i] += 128;
      }
      __builtin_amdgcn_sched_barrier(0);
    }

    // 48 MFMA on register fragments
    #pragma unroll
    for (int ks = 0; ks < 2; ks++)
      #pragma unroll
      for (int gi = 0; gi < 3; gi++)
        #pragma unroll
        for (int mf = 0; mf < 2; mf++)
          #pragma unroll
          for (int nf = 0; nf < 4; nf++)
            acc[gi][mf][nf] = __builtin_amdgcn_mfma_f32_16x16x32_bf16(aF[ks][gi][mf], bF[ks][nf], acc[gi][mf][nf], 0, 0, 0);
  }

  // epilogue (wave-private): gates -> h -> bf16 hws[n'][k] (R6-verified form)
  #pragma unroll
  for (int mf = 0; mf < 2; mf++){
    const int kb = k0 + mf*16 + ((lane >> 4) << 2);   // gate-local k, + r
    float bi[4], bg[4], bo[4];
    #pragma unroll
    for (int r = 0; r < 4; r++){
      bi[r] = b_ih[kb + r]        + b_hh[kb + r];
      bg[r] = b_ih[1024 + kb + r] + b_hh[1024 + kb + r];
      bo[r] = b_ih[1536 + kb + r] + b_hh[1536 + kb + r];
    }
    #pragma unroll
    for (int nf = 0; nf < 4; nf++){
      const int n = nbase + nf*16 + l15;             // n' directly (xws2 order)
      float h[4];
      #pragma unroll
      for (int r = 0; r < 4; r++){
        float iv = acc[0][mf][nf][r] + bi[r];
        float gv = acc[1][mf][nf][r] + bg[r];
        float ov = acc[2][mf][nf][r] + bo[r];
        float ce = sigf(iv) * tanh_fast(gv);
        h[r] = sigf(ov) * tanh_fast(ce);
      }
      uint2 p2;
      p2.x = f2bf(h[0]) | (f2bf(h[1]) << 16);
      p2.y = f2bf(h[2]) | (f2bf(h[3]) << 16);
      *(uint2*)(hws + (size_t)n*H_ + kb) = p2;
    }
  }
}

// ---- Pass 2: out[b2,k,c2] = f32(hws[b2*320+c2][k]) — LDS transpose ---------
__global__ __launch_bounds__(256) void k_out(const unsigned short* __restrict__ hws,
                                             float* __restrict__ out){
  __shared__ float lds[64][65];
  const int tid = threadIdx.x;
  const int kt = blockIdx.x, ctt = blockIdx.y, b2 = blockIdx.z;
  const int k0 = kt*64, n0 = b2*320 + ctt*64;
  const int rr = tid >> 2, q = tid & 3;

  #pragma unroll
  for (int j = 0; j < 2; j++){
    short8 v = *(const short8*)(hws + ((size_t)(n0 + rr))*H_ + k0 + q*16 + j*8);
    #pragma unroll
    for (int e = 0; e < 8; e++)
      lds[rr][q*16 + j*8 + e] = bf2f((unsigned short)v[e]);
  }
  __syncthreads();
  const int krow = rr;
  #pragma unroll
  for (int j = 0; j < 4; j++){
    int c2l = q*16 + j*4;
    float4 o;
    o.x = lds[c2l + 0][krow];
    o.y = lds[c2l + 1][krow];
    o.z = lds[c2l + 2][krow];
    o.w = lds[c2l + 3][krow];
    *(float4*)(out + (size_t)b2*(H_*C_) + (size_t)(k0 + krow)*C_ + ctt*64 + c2l) = o;
  }
}

extern "C" void kernel_launch(void* const* d_in, const int* in_sizes, int n_in,
                              void* d_out, int out_size, void* d_ws, size_t ws_size,
                              hipStream_t stream){
  const float* x    = (const float*)d_in[0];
  const float* w_ih = (const float*)d_in[1];
  // d_in[2] = w_hh is mathematically dead (h0 = 0)
  const float* b_ih = (const float*)d_in[3];
  const float* b_hh = (const float*)d_in[4];
  float* out = (float*)d_out;

  char* ws = (char*)d_ws;
  unsigned short* aws = (unsigned short*)(ws);                           // 1.5 MiB
  unsigned short* xws = (unsigned short*)(ws + 2097152);                 // 10 MiB (n'-order)
  unsigned short* hws = (unsigned short*)(ws + 12582912);                // 10 MiB (hws[n'][k])
  // total workspace use: ~22.5 MiB

  k_prep <<<2048, 256, 0, stream>>>(w_ih, x, aws, xws);
  k_gemm <<<640, 256, 0, stream>>>(aws, xws, b_ih, b_hh, hws);
  k_out  <<<dim3(8, 5, 32), 256, 0, stream>>>(hws, out);
}